// Round 1
// 1053.597 us; speedup vs baseline: 1.3643x; 1.3643x over previous
//
#include <hip/hip_runtime.h>

// GCN-VAE forward, fp32 pipeline, dtype-adaptive inputs, fp32 outputs.
// flag[0] = bf16-view NaN patterns in x   (>64  -> float inputs are fp32)
// flag[1] = zero hi-words in edge pairs   (>E/2 -> edge_index is int64)
// flag[2] = overflow-edge count (ELL slots exceeded; handled by k_spill)
// CSR replaced by ELL (64 slots/node) built with an XCD-sliced windowed kernel.
// Round 4: the monolithic k_mlp (60KB code / 38.6KB scalar stream; VALUBusy 20%,
// 530us) is split into 4 kernels each I$-resident (<16KB code) and K$-resident
// (<8KB weights), with global intermediates reusing the g/h1 workspace regions.

#define NEG 0.01f
#define GS 64        // g row stride (floats) -> 256B rows
#define ELLS 64      // ELL slots per node
#define SLICES 16    // 2 passes x 8 xcd groups
#define SPILL_CAP 65536

static __device__ __forceinline__ float bf2f(unsigned short u) {
    return __uint_as_float(((unsigned)u) << 16);
}
static __device__ __forceinline__ float leaky(float a) { return (a >= 0.f) ? a : NEG * a; }

__global__ void k_zero(int* __restrict__ indeg, int* __restrict__ flag, int n) {
    int i = blockIdx.x * 256 + threadIdx.x;
    if (i < n) indeg[i] = 0;
    if (i == 0) { flag[0] = 0; flag[1] = 0; flag[2] = 0; }
}

// blocks [0,2048): scan N*75 words of x for bf16-view NaN/Inf exponent patterns.
// blocks [2048,4096): scan E word-pairs of edge_index for zero hi-words.
__global__ void k_detect(const unsigned* __restrict__ x, long xwords,
                         const unsigned* __restrict__ ei, long epairs,
                         int* __restrict__ flag) {
    const long stride = 2048L * 256;
    if (blockIdx.x < 2048) {
        long i = (long)blockIdx.x * 256 + threadIdx.x;
        int c = 0;
        for (; i < xwords; i += stride) {
            unsigned w = x[i];
            if (((w >> 23) & 0xFFu) == 0xFFu || ((w >> 7) & 0xFFu) == 0xFFu) c++;
        }
        if (c) atomicAdd(&flag[0], c);
    } else {
        long i = (long)(blockIdx.x - 2048) * 256 + threadIdx.x;
        int c = 0;
        for (; i < epairs; i += stride)
            if (ei[2 * i + 1] == 0u) c++;
        if (c) atomicAdd(&flag[1], c);
    }
}

// ELL build, XCD-sliced: 8192 blocks = 2 passes x (8 xcd-groups x 512).
__global__ void k_build(const int* __restrict__ ei, int* __restrict__ indeg,
                        int* __restrict__ ebuf, int2* __restrict__ spill,
                        int* __restrict__ flag, int E, int N) {
    int blk = blockIdx.x;
    int pass = blk >> 12;           // 0..1
    int x = blk & 7;                // xcd heuristic
    int q = (blk & 4095) >> 3;      // 0..511 within subgroup
    int s = pass * 8 + x;           // slice 0..15
    int sw = (N + SLICES - 1) / SLICES;
    int nlo = s * sw;
    int nhi = nlo + sw; if (nhi > N) nhi = N;
    bool is64 = flag[1] > (E >> 1);
    for (long e = (long)q * 256 + threadIdx.x; e < E; e += 512L * 256) {
        int d = is64 ? ei[2 * (E + e)] : ei[E + e];
        if (d < nlo || d >= nhi) continue;
        int src = is64 ? ei[2 * e] : ei[e];
        if ((unsigned)src >= (unsigned)N) continue;
        int c = atomicAdd(&indeg[d], 1);
        if (c < ELLS) {
            ebuf[(size_t)d * ELLS + c] = src;
        } else {
            int o = atomicAdd(&flag[2], 1);
            if (o < SPILL_CAP) spill[o] = make_int2(src, d);
        }
    }
}

__global__ void k_dinv(const int* __restrict__ indeg, float* __restrict__ dinv, int n) {
    int i = blockIdx.x * 256 + threadIdx.x;
    if (i < n) dinv[i] = rsqrtf(1.0f + (float)indeg[i]);  // deg includes self loop
}

// convert the 16 weight/bias arrays into one fp32 block; block b handles array b.
struct CW {
    const void* src[16];
    int off[16];
    int n[16];
};
__global__ void k_convw(CW cw, float* __restrict__ dst, const int* __restrict__ flag) {
    int b = blockIdx.x;
    bool isf = flag[0] > 64;
    const float* sf = (const float*)cw.src[b];
    const unsigned short* sh = (const unsigned short*)cw.src[b];
    float* d = dst + cw.off[b];
    int n = cw.n[b];
    for (int i = threadIdx.x; i < n; i += 256) d[i] = isf ? sf[i] : bf2f(sh[i]);
}

// weight-block offsets (floats)
#define O_WG 0
#define O_BG 2500
#define O_WE1 2550
#define O_BE1 4550
#define O_WE2 4590
#define O_BE2 5790
#define O_WE3 5820
#define O_BE3 6420
#define O_WFC 6440
#define O_BFC 6540
#define O_WD1 6550
#define O_BD1 6750
#define O_WD2 6770
#define O_BD2 7570
#define O_WD3 7610
#define O_BD3 9610
#define W_TOT 9660

// g[i] = (x[i,100:150] @ Wg.T) * dinv[i]  -> fp32, stride GS
__global__ __launch_bounds__(256) void k_g(const void* __restrict__ xv,
                                           const float* __restrict__ W,
                                           const float* __restrict__ dinv,
                                           const int* __restrict__ flag,
                                           float* __restrict__ g, int n) {
    int i = blockIdx.x * 256 + threadIdx.x;
    if (i >= n) return;
    bool isf = flag[0] > 64;
    float xr[50];
    if (isf) {
        const float* p = (const float*)xv + (size_t)i * 150 + 100;
#pragma unroll
        for (int k = 0; k < 50; k++) xr[k] = p[k];
    } else {
        const unsigned short* p = (const unsigned short*)xv + (size_t)i * 150 + 100;
#pragma unroll
        for (int k = 0; k < 50; k++) xr[k] = bf2f(p[k]);
    }
    const float* Wg = W + O_WG;
    float di = dinv[i];
    float* gr = g + (size_t)i * GS;
#pragma unroll
    for (int f = 0; f < 50; f += 2) {
        float a0 = 0.f, a1 = 0.f;
#pragma unroll
        for (int p = 0; p < 50; p++) {
            a0 += Wg[f * 50 + p] * xr[p];
            a1 += Wg[(f + 1) * 50 + p] * xr[p];
        }
        gr[f] = a0 * di;
        gr[f + 1] = a1 * di;
    }
}

// wave per node: lane f accumulates feature f over ELL edges; 8-way ILP.
__global__ __launch_bounds__(256) void k_gather(const float* __restrict__ g,
                                                const int* __restrict__ indeg,
                                                const int* __restrict__ ebuf,
                                                const float* __restrict__ dinv,
                                                const float* __restrict__ W,
                                                float* __restrict__ h1, int n) {
    int wid = threadIdx.x >> 6;
    int lane = threadIdx.x & 63;
    int i = blockIdx.x * 4 + wid;
    if (i >= n) return;
    int fc = lane < 50 ? lane : 49;  // clamp: lanes 50..63 never stored
    int cnt = indeg[i];
    if (cnt > ELLS) cnt = ELLS;
    float di = dinv[i];
    int ev = (lane < cnt) ? ebuf[(size_t)i * ELLS + lane] : 0;
    float a0 = g[(size_t)i * GS + fc];  // self-loop term (g pre-scaled by dinv[src])
    float a1 = 0.f, a2 = 0.f, a3 = 0.f, a4 = 0.f, a5 = 0.f, a6 = 0.f, a7 = 0.f;
    int m = 0;
    for (; m + 7 < cnt; m += 8) {
        int j0 = __shfl(ev, m);
        int j1 = __shfl(ev, m + 1);
        int j2 = __shfl(ev, m + 2);
        int j3 = __shfl(ev, m + 3);
        int j4 = __shfl(ev, m + 4);
        int j5 = __shfl(ev, m + 5);
        int j6 = __shfl(ev, m + 6);
        int j7 = __shfl(ev, m + 7);
        a0 += g[(size_t)j0 * GS + fc];
        a1 += g[(size_t)j1 * GS + fc];
        a2 += g[(size_t)j2 * GS + fc];
        a3 += g[(size_t)j3 * GS + fc];
        a4 += g[(size_t)j4 * GS + fc];
        a5 += g[(size_t)j5 * GS + fc];
        a6 += g[(size_t)j6 * GS + fc];
        a7 += g[(size_t)j7 * GS + fc];
    }
    for (; m < cnt; m++) {
        int j = __shfl(ev, m);
        a0 += g[(size_t)j * GS + fc];
    }
    if (lane < 50) {
        float h = (((a0 + a1) + (a2 + a3)) + ((a4 + a5) + (a6 + a7))) * di + W[O_BG + lane];
        h1[(size_t)i * 50 + lane] = h;
    }
}

// overflow edges (deg > ELLS): atomic-add their contribution into h1.
__global__ void k_spill(const int2* __restrict__ spill, const int* __restrict__ flag,
                        const float* __restrict__ g, const float* __restrict__ dinv,
                        float* __restrict__ h1) {
    int nov = flag[2];
    if (nov > SPILL_CAP) nov = SPILL_CAP;
    int lane = threadIdx.x & 63;
    int wave = (blockIdx.x * 256 + threadIdx.x) >> 6;
    for (int e = wave; e < nov; e += gridDim.x * 4) {
        int2 sd = spill[e];
        if (lane < 50)
            atomicAdd(&h1[(size_t)sd.y * 50 + lane], g[(size_t)sd.x * GS + lane] * dinv[sd.y]);
    }
}

// ---- MLP split: each kernel has <16KB code and <8KB scalar weight stream ----

// e1: t1[i,0:40] = leaky(h1[i,:] @ We1.T + be1)
__global__ __launch_bounds__(256) void k_e1(const float* __restrict__ h1,
                                            const float* __restrict__ W,
                                            float* __restrict__ t1, int n) {
    int i = blockIdx.x * 256 + threadIdx.x;
    if (i >= n) return;
    float v0[50];
    const float2* hr = (const float2*)(h1 + (size_t)i * 50);
#pragma unroll
    for (int p = 0; p < 25; p++) {
        float2 q = hr[p];
        v0[2 * p] = q.x;
        v0[2 * p + 1] = q.y;
    }
    float o[40];
#pragma unroll
    for (int f = 0; f < 40; f++) {
        float a = W[O_BE1 + f];
#pragma unroll
        for (int p = 0; p < 50; p++) a += W[O_WE1 + f * 50 + p] * v0[p];
        o[f] = leaky(a);
    }
    float4* ot = (float4*)(t1 + (size_t)i * 40);
#pragma unroll
    for (int p = 0; p < 10; p++) ot[p] = make_float4(o[4 * p], o[4 * p + 1], o[4 * p + 2], o[4 * p + 3]);
}

// e2+e3: reads t1, writes mu -> out[n*50 + i*10], log_var -> out[n*60 + i*10]
__global__ __launch_bounds__(256) void k_e23(const float* __restrict__ t1,
                                             const float* __restrict__ W,
                                             float* __restrict__ out, int n) {
    int i = blockIdx.x * 256 + threadIdx.x;
    if (i >= n) return;
    float v1[40];
    const float4* tr = (const float4*)(t1 + (size_t)i * 40);
#pragma unroll
    for (int p = 0; p < 10; p++) {
        float4 q = tr[p];
        v1[4 * p] = q.x; v1[4 * p + 1] = q.y; v1[4 * p + 2] = q.z; v1[4 * p + 3] = q.w;
    }
    float v2[30];
#pragma unroll
    for (int f = 0; f < 30; f++) {
        float a = W[O_BE2 + f];
#pragma unroll
        for (int p = 0; p < 40; p++) a += W[O_WE2 + f * 40 + p] * v1[p];
        v2[f] = leaky(a);
    }
    float v3[20];  // [mu(10) | log_var(10)]
#pragma unroll
    for (int f = 0; f < 20; f++) {
        float a = W[O_BE3 + f];
#pragma unroll
        for (int p = 0; p < 30; p++) a += W[O_WE3 + f * 30 + p] * v2[p];
        v3[f] = a;
    }
    float2* o_mu = (float2*)(out + (size_t)n * 50 + (size_t)i * 10);
    float2* o_lv = (float2*)(out + (size_t)n * 60 + (size_t)i * 10);
#pragma unroll
    for (int p = 0; p < 5; p++) {
        o_mu[p] = make_float2(v3[2 * p], v3[2 * p + 1]);
        o_lv[p] = make_float2(v3[10 + 2 * p], v3[10 + 2 * p + 1]);
    }
}

// reparam + fc + d1 + d2: reads mu/log_var from out, eps; writes z -> out[n*70+i*10],
// d2 activations -> t3[i*40] (reuses h1's region).
__global__ __launch_bounds__(256) void k_zfc(float* outb,  // same buffer read+write, disjoint regions
                                             const void* __restrict__ epsv,
                                             const float* __restrict__ W,
                                             const int* __restrict__ flag,
                                             float* __restrict__ t3, int n) {
    int i = blockIdx.x * 256 + threadIdx.x;
    if (i >= n) return;
    bool isf = flag[0] > 64;
    float mu[10], lv[10];
    const float2* pm = (const float2*)(outb + (size_t)n * 50 + (size_t)i * 10);
    const float2* pl = (const float2*)(outb + (size_t)n * 60 + (size_t)i * 10);
#pragma unroll
    for (int p = 0; p < 5; p++) {
        float2 a = pm[p]; mu[2 * p] = a.x; mu[2 * p + 1] = a.y;
        float2 b = pl[p]; lv[2 * p] = b.x; lv[2 * p + 1] = b.y;
    }
    float ev[10];
    if (isf) {
        const float* p = (const float*)epsv + (size_t)i * 10;
#pragma unroll
        for (int k = 0; k < 10; k++) ev[k] = p[k];
    } else {
        const unsigned short* p = (const unsigned short*)epsv + (size_t)i * 10;
#pragma unroll
        for (int k = 0; k < 10; k++) ev[k] = bf2f(p[k]);
    }
    float z1[10];
#pragma unroll
    for (int k = 0; k < 10; k++) z1[k] = mu[k] + ev[k] * expf(0.5f * lv[k]);
    float z[10];
#pragma unroll
    for (int f = 0; f < 10; f++) {
        float a = W[O_BFC + f];
#pragma unroll
        for (int p = 0; p < 10; p++) a += W[O_WFC + f * 10 + p] * z1[p];
        z[f] = (a > 0.f) ? a : 0.f;
    }
    float2* o_z = (float2*)(outb + (size_t)n * 70 + (size_t)i * 10);
#pragma unroll
    for (int p = 0; p < 5; p++) o_z[p] = make_float2(z[2 * p], z[2 * p + 1]);
    float d1[20];
#pragma unroll
    for (int f = 0; f < 20; f++) {
        float a = W[O_BD1 + f];
#pragma unroll
        for (int p = 0; p < 10; p++) a += W[O_WD1 + f * 10 + p] * z[p];
        d1[f] = leaky(a);
    }
    float d2[40];
#pragma unroll
    for (int f = 0; f < 40; f++) {
        float a = W[O_BD2 + f];
#pragma unroll
        for (int p = 0; p < 20; p++) a += W[O_WD2 + f * 20 + p] * d1[p];
        d2[f] = leaky(a);
    }
    float4* ot = (float4*)(t3 + (size_t)i * 40);
#pragma unroll
    for (int p = 0; p < 10; p++)
        ot[p] = make_float4(d2[4 * p], d2[4 * p + 1], d2[4 * p + 2], d2[4 * p + 3]);
}

// d3 + sigmoid: reads t3, writes mu_prime -> out[i*50]
__global__ __launch_bounds__(256) void k_d3(const float* __restrict__ t3,
                                            const float* __restrict__ W,
                                            float* __restrict__ out, int n) {
    int i = blockIdx.x * 256 + threadIdx.x;
    if (i >= n) return;
    float d2[40];
    const float4* tr = (const float4*)(t3 + (size_t)i * 40);
#pragma unroll
    for (int p = 0; p < 10; p++) {
        float4 q = tr[p];
        d2[4 * p] = q.x; d2[4 * p + 1] = q.y; d2[4 * p + 2] = q.z; d2[4 * p + 3] = q.w;
    }
    float o[50];
#pragma unroll
    for (int f = 0; f < 50; f++) {
        float a = W[O_BD3 + f];
#pragma unroll
        for (int p = 0; p < 40; p++) a += W[O_WD3 + f * 40 + p] * d2[p];
        o[f] = 1.f / (1.f + expf(-a));
    }
    float2* om = (float2*)(out + (size_t)i * 50);
#pragma unroll
    for (int p = 0; p < 25; p++) om[p] = make_float2(o[2 * p], o[2 * p + 1]);
}

extern "C" void kernel_launch(void* const* d_in, const int* in_sizes, int n_in,
                              void* d_out, int out_size, void* d_ws, size_t ws_size,
                              hipStream_t stream) {
    const int N = in_sizes[0] / 150;
    const int E = in_sizes[1] / 2;

    char* w = (char*)d_ws;
    auto alloc = [&](size_t bytes) {
        void* p = (void*)w;
        w += (bytes + 255) & ~(size_t)255;
        return p;
    };
    int* indeg = (int*)alloc((size_t)N * 4);
    int* flag = (int*)alloc(256);
    float* dinv = (float*)alloc((size_t)N * 4);
    float* Wall = (float*)alloc((size_t)W_TOT * 4);
    int2* spill = (int2*)alloc((size_t)SPILL_CAP * 8);
    float* g = (float*)alloc((size_t)N * GS * 4);
    float* h1 = (float*)alloc((size_t)N * 50 * 4);
    int* ebuf = (int*)alloc((size_t)N * ELLS * 4);

    // intermediate reuse: t1 (N*40) lives in g's region (g dead after k_spill);
    // t3 (N*40) lives in h1's region (h1 dead after k_e1).
    float* t1 = g;
    float* t3 = h1;

    CW cw;
    static const int wn[16] = {2500, 50, 2000, 40, 1200, 30, 600, 20,
                               100, 10, 200, 20, 800, 40, 2000, 50};
    static const int wo[16] = {O_WG, O_BG, O_WE1, O_BE1, O_WE2, O_BE2, O_WE3, O_BE3,
                               O_WFC, O_BFC, O_WD1, O_BD1, O_WD2, O_BD2, O_WD3, O_BD3};
    for (int k = 0; k < 16; k++) {
        cw.src[k] = d_in[3 + k];
        cw.off[k] = wo[k];
        cw.n[k] = wn[k];
    }

    int nbN = (N + 255) / 256;

    k_zero<<<nbN, 256, 0, stream>>>(indeg, flag, N);
    k_detect<<<4096, 256, 0, stream>>>((const unsigned*)d_in[0], (long)N * 75,
                                       (const unsigned*)d_in[1], (long)E, flag);
    k_build<<<8192, 256, 0, stream>>>((const int*)d_in[1], indeg, ebuf, spill, flag, E, N);
    k_dinv<<<nbN, 256, 0, stream>>>(indeg, dinv, N);
    k_convw<<<16, 256, 0, stream>>>(cw, Wall, flag);
    k_g<<<nbN, 256, 0, stream>>>(d_in[0], Wall, dinv, flag, g, N);
    k_gather<<<(N + 3) / 4, 256, 0, stream>>>(g, indeg, ebuf, dinv, Wall, h1, N);
    k_spill<<<64, 256, 0, stream>>>(spill, flag, g, dinv, h1);
    k_e1<<<nbN, 256, 0, stream>>>(h1, Wall, t1, N);
    k_e23<<<nbN, 256, 0, stream>>>(t1, Wall, (float*)d_out, N);
    k_zfc<<<nbN, 256, 0, stream>>>((float*)d_out, d_in[2], Wall, flag, t3, N);
    k_d3<<<nbN, 256, 0, stream>>>(t3, Wall, (float*)d_out, N);
}

// Round 3
// 1027.624 us; speedup vs baseline: 1.3988x; 1.0253x over previous
//
#include <hip/hip_runtime.h>

// GCN-VAE forward, fp32 pipeline, dtype-adaptive inputs, fp32 outputs.
// flag[0] = bf16-view NaN patterns in x sample   (>64        -> float inputs are fp32)
// flag[1] = zero hi-words in edge-pair sample    (>DET_ES/2  -> edge_index is int64)
// flag[2] = overflow-edge count (ELL slots exceeded; handled by k_spill)
// Round 5: k_build was L2-thrash bound (FETCH 375MB / WRITE 339MB vs ~150MB ideal):
// the int64 dst stream (51.2MB x 16 slices) evicted the 3.2MB ELL window from L2,
// causing partial-dirty writebacks + refetches. Fix: (a) one-pass int32 edge
// compaction (overlaid on g region), (b) non-temporal (evict-first) loads for the
// stream so the window stays L2-resident, (c) k_detect full scan -> 12MB sample.
// Round 6: fix compile error — __builtin_nontemporal_load needs a clang native
// vector type, not HIP's int4 class. Use ext_vector_type(4) int.

#define NEG 0.01f
#define GS 64        // g row stride (floats) -> 256B rows
#define ELLS 64      // ELL slots per node
#define SLICES 16    // 2 passes x 8 xcd groups
#define SPILL_CAP 65536

// detect sampling: 1024 chunks x 1024 words/pairs per side
#define DET_ES (1024 * 1024)
#define IS64_THRESH (DET_ES / 2)

typedef int vint4 __attribute__((ext_vector_type(4)));

static __device__ __forceinline__ float bf2f(unsigned short u) {
    return __uint_as_float(((unsigned)u) << 16);
}
static __device__ __forceinline__ float leaky(float a) { return (a >= 0.f) ? a : NEG * a; }

__global__ void k_zero(int* __restrict__ indeg, int* __restrict__ flag, int n) {
    int i = blockIdx.x * 256 + threadIdx.x;
    if (i < n) indeg[i] = 0;
    if (i == 0) { flag[0] = 0; flag[1] = 0; flag[2] = 0; }
}

// Sampled dtype detection. 512 blocks: waves 0..1023 sample x words,
// waves 1024..2047 sample edge hi-words. Each wave reads one coalesced
// 1024-word chunk; chunks spread evenly across the array.
__global__ void k_detect(const unsigned* __restrict__ x, long xwords,
                         const unsigned* __restrict__ ei, long epairs,
                         int* __restrict__ flag) {
    int gw = (blockIdx.x * 256 + threadIdx.x) >> 6;  // 0..2047
    int lane = threadIdx.x & 63;
    int side = gw >> 10;
    int ch = gw & 1023;
    int c = 0;
    if (side == 0) {
        long step = xwords >> 10;
        long base = (long)ch * step;
        if (base + 1024 > xwords) base = xwords > 1024 ? xwords - 1024 : 0;
#pragma unroll
        for (int t = 0; t < 16; t++) {
            long idx = base + t * 64 + lane;
            if (idx < xwords) {
                unsigned w = x[idx];
                if (((w >> 23) & 0xFFu) == 0xFFu || ((w >> 7) & 0xFFu) == 0xFFu) c++;
            }
        }
        for (int k = 32; k; k >>= 1) c += __shfl_xor(c, k);
        if (lane == 0 && c) atomicAdd(&flag[0], c);
    } else {
        long step = epairs >> 10;
        long base = (long)ch * step;
        if (base + 1024 > epairs) base = epairs > 1024 ? epairs - 1024 : 0;
#pragma unroll
        for (int t = 0; t < 16; t++) {
            long idx = base + t * 64 + lane;
            if (idx < epairs && ei[2 * idx + 1] == 0u) c++;
        }
        for (int k = 32; k; k >>= 1) c += __shfl_xor(c, k);
        if (lane == 0 && c) atomicAdd(&flag[1], c);
    }
}

// One-pass edge compaction to int32 src32/dst32 (coalesced both sides).
__global__ void k_compact(const unsigned* __restrict__ ei, const int* __restrict__ flag,
                          int* __restrict__ src32, int* __restrict__ dst32, long E) {
    bool is64 = flag[1] > IS64_THRESH;
    long i = (long)blockIdx.x * 256 + threadIdx.x;
    const long stride = 2048L * 256;
    if (is64) {
        const int2* p = (const int2*)ei;
        for (; i < E; i += stride) {
            src32[i] = p[i].x;
            dst32[i] = p[E + i].x;
        }
    } else {
        const int* p = (const int*)ei;
        for (; i < E; i += stride) {
            src32[i] = p[i];
            dst32[i] = p[E + i];
        }
    }
}

// ELL build, XCD-sliced: 8192 blocks = 2 passes x (8 xcd-groups x 512).
// Streams dst32/src32 with non-temporal (evict-first) loads so the 3.2MB
// ELL window per XCD stays L2-resident; 16B vector loads for the dst scan.
__global__ __launch_bounds__(256) void k_build(const int* __restrict__ src32,
                        const int* __restrict__ dst32, int* __restrict__ indeg,
                        int* __restrict__ ebuf, int2* __restrict__ spill,
                        int* __restrict__ flag, int E, int N) {
    int blk = blockIdx.x;
    int pass = blk >> 12;           // 0..1
    int xg = blk & 7;               // xcd heuristic
    int q = (blk & 4095) >> 3;      // 0..511 within subgroup
    int s = pass * 8 + xg;          // slice 0..15
    int sw = (N + SLICES - 1) / SLICES;
    int nlo = s * sw;
    int nhi = nlo + sw; if (nhi > N) nhi = N;
    const long step = 512L * 256 * 4;
    for (long e0 = ((long)q * 256 + threadIdx.x) * 4; e0 < E; e0 += step) {
        int dv[4];
        if (e0 + 4 <= E) {
            vint4 t = __builtin_nontemporal_load((const vint4*)(dst32 + e0));
            dv[0] = t.x; dv[1] = t.y; dv[2] = t.z; dv[3] = t.w;
        } else {
            for (int k = 0; k < 4; k++) dv[k] = (e0 + k < E) ? dst32[e0 + k] : -1;
        }
#pragma unroll
        for (int k = 0; k < 4; k++) {
            int d = dv[k];
            if (d < nlo || d >= nhi) continue;
            int src = __builtin_nontemporal_load(&src32[e0 + k]);
            if ((unsigned)src >= (unsigned)N) continue;
            int c = atomicAdd(&indeg[d], 1);
            if (c < ELLS) {
                ebuf[(size_t)d * ELLS + c] = src;
            } else {
                int o = atomicAdd(&flag[2], 1);
                if (o < SPILL_CAP) spill[o] = make_int2(src, d);
            }
        }
    }
}

__global__ void k_dinv(const int* __restrict__ indeg, float* __restrict__ dinv, int n) {
    int i = blockIdx.x * 256 + threadIdx.x;
    if (i < n) dinv[i] = rsqrtf(1.0f + (float)indeg[i]);  // deg includes self loop
}

// convert the 16 weight/bias arrays into one fp32 block; block b handles array b.
struct CW {
    const void* src[16];
    int off[16];
    int n[16];
};
__global__ void k_convw(CW cw, float* __restrict__ dst, const int* __restrict__ flag) {
    int b = blockIdx.x;
    bool isf = flag[0] > 64;
    const float* sf = (const float*)cw.src[b];
    const unsigned short* sh = (const unsigned short*)cw.src[b];
    float* d = dst + cw.off[b];
    int n = cw.n[b];
    for (int i = threadIdx.x; i < n; i += 256) d[i] = isf ? sf[i] : bf2f(sh[i]);
}

// weight-block offsets (floats)
#define O_WG 0
#define O_BG 2500
#define O_WE1 2550
#define O_BE1 4550
#define O_WE2 4590
#define O_BE2 5790
#define O_WE3 5820
#define O_BE3 6420
#define O_WFC 6440
#define O_BFC 6540
#define O_WD1 6550
#define O_BD1 6750
#define O_WD2 6770
#define O_BD2 7570
#define O_WD3 7610
#define O_BD3 9610
#define W_TOT 9660

// g[i] = (x[i,100:150] @ Wg.T) * dinv[i]  -> fp32, stride GS
__global__ __launch_bounds__(256) void k_g(const void* __restrict__ xv,
                                           const float* __restrict__ W,
                                           const float* __restrict__ dinv,
                                           const int* __restrict__ flag,
                                           float* __restrict__ g, int n) {
    int i = blockIdx.x * 256 + threadIdx.x;
    if (i >= n) return;
    bool isf = flag[0] > 64;
    float xr[50];
    if (isf) {
        const float* p = (const float*)xv + (size_t)i * 150 + 100;
#pragma unroll
        for (int k = 0; k < 50; k++) xr[k] = p[k];
    } else {
        const unsigned short* p = (const unsigned short*)xv + (size_t)i * 150 + 100;
#pragma unroll
        for (int k = 0; k < 50; k++) xr[k] = bf2f(p[k]);
    }
    const float* Wg = W + O_WG;
    float di = dinv[i];
    float* gr = g + (size_t)i * GS;
#pragma unroll
    for (int f = 0; f < 50; f += 2) {
        float a0 = 0.f, a1 = 0.f;
#pragma unroll
        for (int p = 0; p < 50; p++) {
            a0 += Wg[f * 50 + p] * xr[p];
            a1 += Wg[(f + 1) * 50 + p] * xr[p];
        }
        gr[f] = a0 * di;
        gr[f + 1] = a1 * di;
    }
}

// wave per node: lane f accumulates feature f over ELL edges; 8-way ILP.
__global__ __launch_bounds__(256) void k_gather(const float* __restrict__ g,
                                                const int* __restrict__ indeg,
                                                const int* __restrict__ ebuf,
                                                const float* __restrict__ dinv,
                                                const float* __restrict__ W,
                                                float* __restrict__ h1, int n) {
    int wid = threadIdx.x >> 6;
    int lane = threadIdx.x & 63;
    int i = blockIdx.x * 4 + wid;
    if (i >= n) return;
    int fc = lane < 50 ? lane : 49;  // clamp: lanes 50..63 never stored
    int cnt = indeg[i];
    if (cnt > ELLS) cnt = ELLS;
    float di = dinv[i];
    int ev = (lane < cnt) ? ebuf[(size_t)i * ELLS + lane] : 0;
    float a0 = g[(size_t)i * GS + fc];  // self-loop term (g pre-scaled by dinv[src])
    float a1 = 0.f, a2 = 0.f, a3 = 0.f, a4 = 0.f, a5 = 0.f, a6 = 0.f, a7 = 0.f;
    int m = 0;
    for (; m + 7 < cnt; m += 8) {
        int j0 = __shfl(ev, m);
        int j1 = __shfl(ev, m + 1);
        int j2 = __shfl(ev, m + 2);
        int j3 = __shfl(ev, m + 3);
        int j4 = __shfl(ev, m + 4);
        int j5 = __shfl(ev, m + 5);
        int j6 = __shfl(ev, m + 6);
        int j7 = __shfl(ev, m + 7);
        a0 += g[(size_t)j0 * GS + fc];
        a1 += g[(size_t)j1 * GS + fc];
        a2 += g[(size_t)j2 * GS + fc];
        a3 += g[(size_t)j3 * GS + fc];
        a4 += g[(size_t)j4 * GS + fc];
        a5 += g[(size_t)j5 * GS + fc];
        a6 += g[(size_t)j6 * GS + fc];
        a7 += g[(size_t)j7 * GS + fc];
    }
    for (; m < cnt; m++) {
        int j = __shfl(ev, m);
        a0 += g[(size_t)j * GS + fc];
    }
    if (lane < 50) {
        float h = (((a0 + a1) + (a2 + a3)) + ((a4 + a5) + (a6 + a7))) * di + W[O_BG + lane];
        h1[(size_t)i * 50 + lane] = h;
    }
}

// overflow edges (deg > ELLS): atomic-add their contribution into h1.
__global__ void k_spill(const int2* __restrict__ spill, const int* __restrict__ flag,
                        const float* __restrict__ g, const float* __restrict__ dinv,
                        float* __restrict__ h1) {
    int nov = flag[2];
    if (nov > SPILL_CAP) nov = SPILL_CAP;
    int lane = threadIdx.x & 63;
    int wave = (blockIdx.x * 256 + threadIdx.x) >> 6;
    for (int e = wave; e < nov; e += gridDim.x * 4) {
        int2 sd = spill[e];
        if (lane < 50)
            atomicAdd(&h1[(size_t)sd.y * 50 + lane], g[(size_t)sd.x * GS + lane] * dinv[sd.y]);
    }
}

// ---- MLP split: each kernel has <16KB code and <8KB scalar weight stream ----

// e1: t1[i,0:40] = leaky(h1[i,:] @ We1.T + be1)
__global__ __launch_bounds__(256) void k_e1(const float* __restrict__ h1,
                                            const float* __restrict__ W,
                                            float* __restrict__ t1, int n) {
    int i = blockIdx.x * 256 + threadIdx.x;
    if (i >= n) return;
    float v0[50];
    const float2* hr = (const float2*)(h1 + (size_t)i * 50);
#pragma unroll
    for (int p = 0; p < 25; p++) {
        float2 q = hr[p];
        v0[2 * p] = q.x;
        v0[2 * p + 1] = q.y;
    }
    float o[40];
#pragma unroll
    for (int f = 0; f < 40; f++) {
        float a = W[O_BE1 + f];
#pragma unroll
        for (int p = 0; p < 50; p++) a += W[O_WE1 + f * 50 + p] * v0[p];
        o[f] = leaky(a);
    }
    float4* ot = (float4*)(t1 + (size_t)i * 40);
#pragma unroll
    for (int p = 0; p < 10; p++) ot[p] = make_float4(o[4 * p], o[4 * p + 1], o[4 * p + 2], o[4 * p + 3]);
}

// e2+e3: reads t1, writes mu -> out[n*50 + i*10], log_var -> out[n*60 + i*10]
__global__ __launch_bounds__(256) void k_e23(const float* __restrict__ t1,
                                             const float* __restrict__ W,
                                             float* __restrict__ out, int n) {
    int i = blockIdx.x * 256 + threadIdx.x;
    if (i >= n) return;
    float v1[40];
    const float4* tr = (const float4*)(t1 + (size_t)i * 40);
#pragma unroll
    for (int p = 0; p < 10; p++) {
        float4 q = tr[p];
        v1[4 * p] = q.x; v1[4 * p + 1] = q.y; v1[4 * p + 2] = q.z; v1[4 * p + 3] = q.w;
    }
    float v2[30];
#pragma unroll
    for (int f = 0; f < 30; f++) {
        float a = W[O_BE2 + f];
#pragma unroll
        for (int p = 0; p < 40; p++) a += W[O_WE2 + f * 40 + p] * v1[p];
        v2[f] = leaky(a);
    }
    float v3[20];  // [mu(10) | log_var(10)]
#pragma unroll
    for (int f = 0; f < 20; f++) {
        float a = W[O_BE3 + f];
#pragma unroll
        for (int p = 0; p < 30; p++) a += W[O_WE3 + f * 30 + p] * v2[p];
        v3[f] = a;
    }
    float2* o_mu = (float2*)(out + (size_t)n * 50 + (size_t)i * 10);
    float2* o_lv = (float2*)(out + (size_t)n * 60 + (size_t)i * 10);
#pragma unroll
    for (int p = 0; p < 5; p++) {
        o_mu[p] = make_float2(v3[2 * p], v3[2 * p + 1]);
        o_lv[p] = make_float2(v3[10 + 2 * p], v3[10 + 2 * p + 1]);
    }
}

// reparam + fc + d1 + d2: reads mu/log_var from out, eps; writes z -> out[n*70+i*10],
// d2 activations -> t3[i*40] (reuses h1's region).
__global__ __launch_bounds__(256) void k_zfc(float* outb,  // same buffer read+write, disjoint regions
                                             const void* __restrict__ epsv,
                                             const float* __restrict__ W,
                                             const int* __restrict__ flag,
                                             float* __restrict__ t3, int n) {
    int i = blockIdx.x * 256 + threadIdx.x;
    if (i >= n) return;
    bool isf = flag[0] > 64;
    float mu[10], lv[10];
    const float2* pm = (const float2*)(outb + (size_t)n * 50 + (size_t)i * 10);
    const float2* pl = (const float2*)(outb + (size_t)n * 60 + (size_t)i * 10);
#pragma unroll
    for (int p = 0; p < 5; p++) {
        float2 a = pm[p]; mu[2 * p] = a.x; mu[2 * p + 1] = a.y;
        float2 b = pl[p]; lv[2 * p] = b.x; lv[2 * p + 1] = b.y;
    }
    float ev[10];
    if (isf) {
        const float* p = (const float*)epsv + (size_t)i * 10;
#pragma unroll
        for (int k = 0; k < 10; k++) ev[k] = p[k];
    } else {
        const unsigned short* p = (const unsigned short*)epsv + (size_t)i * 10;
#pragma unroll
        for (int k = 0; k < 10; k++) ev[k] = bf2f(p[k]);
    }
    float z1[10];
#pragma unroll
    for (int k = 0; k < 10; k++) z1[k] = mu[k] + ev[k] * expf(0.5f * lv[k]);
    float z[10];
#pragma unroll
    for (int f = 0; f < 10; f++) {
        float a = W[O_BFC + f];
#pragma unroll
        for (int p = 0; p < 10; p++) a += W[O_WFC + f * 10 + p] * z1[p];
        z[f] = (a > 0.f) ? a : 0.f;
    }
    float2* o_z = (float2*)(outb + (size_t)n * 70 + (size_t)i * 10);
#pragma unroll
    for (int p = 0; p < 5; p++) o_z[p] = make_float2(z[2 * p], z[2 * p + 1]);
    float d1[20];
#pragma unroll
    for (int f = 0; f < 20; f++) {
        float a = W[O_BD1 + f];
#pragma unroll
        for (int p = 0; p < 10; p++) a += W[O_WD1 + f * 10 + p] * z[p];
        d1[f] = leaky(a);
    }
    float d2[40];
#pragma unroll
    for (int f = 0; f < 40; f++) {
        float a = W[O_BD2 + f];
#pragma unroll
        for (int p = 0; p < 20; p++) a += W[O_WD2 + f * 20 + p] * d1[p];
        d2[f] = leaky(a);
    }
    float4* ot = (float4*)(t3 + (size_t)i * 40);
#pragma unroll
    for (int p = 0; p < 10; p++)
        ot[p] = make_float4(d2[4 * p], d2[4 * p + 1], d2[4 * p + 2], d2[4 * p + 3]);
}

// d3 + sigmoid: reads t3, writes mu_prime -> out[i*50]
__global__ __launch_bounds__(256) void k_d3(const float* __restrict__ t3,
                                            const float* __restrict__ W,
                                            float* __restrict__ out, int n) {
    int i = blockIdx.x * 256 + threadIdx.x;
    if (i >= n) return;
    float d2[40];
    const float4* tr = (const float4*)(t3 + (size_t)i * 40);
#pragma unroll
    for (int p = 0; p < 10; p++) {
        float4 q = tr[p];
        d2[4 * p] = q.x; d2[4 * p + 1] = q.y; d2[4 * p + 2] = q.z; d2[4 * p + 3] = q.w;
    }
    float o[50];
#pragma unroll
    for (int f = 0; f < 50; f++) {
        float a = W[O_BD3 + f];
#pragma unroll
        for (int p = 0; p < 40; p++) a += W[O_WD3 + f * 40 + p] * d2[p];
        o[f] = 1.f / (1.f + expf(-a));
    }
    float2* om = (float2*)(out + (size_t)i * 50);
#pragma unroll
    for (int p = 0; p < 25; p++) om[p] = make_float2(o[2 * p], o[2 * p + 1]);
}

extern "C" void kernel_launch(void* const* d_in, const int* in_sizes, int n_in,
                              void* d_out, int out_size, void* d_ws, size_t ws_size,
                              hipStream_t stream) {
    const int N = in_sizes[0] / 150;
    const int E = in_sizes[1] / 2;

    char* w = (char*)d_ws;
    auto alloc = [&](size_t bytes) {
        void* p = (void*)w;
        w += (bytes + 255) & ~(size_t)255;
        return p;
    };
    int* indeg = (int*)alloc((size_t)N * 4);
    int* flag = (int*)alloc(256);
    float* dinv = (float*)alloc((size_t)N * 4);
    float* Wall = (float*)alloc((size_t)W_TOT * 4);
    int2* spill = (int2*)alloc((size_t)SPILL_CAP * 8);
    float* g = (float*)alloc((size_t)N * GS * 4);
    float* h1 = (float*)alloc((size_t)N * 50 * 4);
    int* ebuf = (int*)alloc((size_t)N * ELLS * 4);

    // int32 edge arrays live in g's region (g is written only later, by k_g);
    // fall back to fresh workspace if the region is too small.
    int* dst32;
    int* src32;
    if (2L * E <= (long)N * GS) {
        dst32 = (int*)g;
        src32 = (int*)g + E;
    } else {
        dst32 = (int*)alloc((size_t)E * 4);
        src32 = (int*)alloc((size_t)E * 4);
    }

    // intermediate reuse: t1 (N*40) lives in g's region (g dead after k_spill);
    // t3 (N*40) lives in h1's region (h1 dead after k_e1).
    float* t1 = g;
    float* t3 = h1;

    CW cw;
    static const int wn[16] = {2500, 50, 2000, 40, 1200, 30, 600, 20,
                               100, 10, 200, 20, 800, 40, 2000, 50};
    static const int wo[16] = {O_WG, O_BG, O_WE1, O_BE1, O_WE2, O_BE2, O_WE3, O_BE3,
                               O_WFC, O_BFC, O_WD1, O_BD1, O_WD2, O_BD2, O_WD3, O_BD3};
    for (int k = 0; k < 16; k++) {
        cw.src[k] = d_in[3 + k];
        cw.off[k] = wo[k];
        cw.n[k] = wn[k];
    }

    int nbN = (N + 255) / 256;

    k_zero<<<nbN, 256, 0, stream>>>(indeg, flag, N);
    k_detect<<<512, 256, 0, stream>>>((const unsigned*)d_in[0], (long)N * 75,
                                      (const unsigned*)d_in[1], (long)E, flag);
    k_compact<<<2048, 256, 0, stream>>>((const unsigned*)d_in[1], flag, src32, dst32, (long)E);
    k_build<<<8192, 256, 0, stream>>>(src32, dst32, indeg, ebuf, spill, flag, E, N);
    k_dinv<<<nbN, 256, 0, stream>>>(indeg, dinv, N);
    k_convw<<<16, 256, 0, stream>>>(cw, Wall, flag);
    k_g<<<nbN, 256, 0, stream>>>(d_in[0], Wall, dinv, flag, g, N);
    k_gather<<<(N + 3) / 4, 256, 0, stream>>>(g, indeg, ebuf, dinv, Wall, h1, N);
    k_spill<<<64, 256, 0, stream>>>(spill, flag, g, dinv, h1);
    k_e1<<<nbN, 256, 0, stream>>>(h1, Wall, t1, N);
    k_e23<<<nbN, 256, 0, stream>>>(t1, Wall, (float*)d_out, N);
    k_zfc<<<nbN, 256, 0, stream>>>((float*)d_out, d_in[2], Wall, flag, t3, N);
    k_d3<<<nbN, 256, 0, stream>>>(t3, Wall, (float*)d_out, N);
}